// Round 6
// baseline (298.105 us; speedup 1.0000x reference)
//
#include <hip/hip_runtime.h>
#include <math.h>

#define B_G   256
#define IN_D  128
#define FD    256
#define HID   256
#define OUT_D 128
#define TXT   512
#define NTILES 511          // N = 65408 = 511 * 128 exactly
#define XKS   136           // LDS k-stride for staged Xbf tile (ushorts)

typedef short bf16x8 __attribute__((ext_vector_type(8)));
typedef float f32x4  __attribute__((ext_vector_type(4)));

__device__ __forceinline__ f32x4 MFMA(bf16x8 a, bf16x8 b, f32x4 c) {
    return __builtin_amdgcn_mfma_f32_16x16x32_bf16(a, b, c, 0, 0, 0);
}

// ---------------------------------------------------------------------------
// bf16 helpers (RNE)
// ---------------------------------------------------------------------------
__device__ __forceinline__ unsigned bf_rne(float x) {
    unsigned u = __float_as_uint(x);
    u += 0x7fffu + ((u >> 16) & 1u);
    return u >> 16;
}
__device__ __forceinline__ float bf_to_f(unsigned h) {
    return __uint_as_float(h << 16);
}
__device__ __forceinline__ bf16x8 pack_hi8(const float4& v0, const float4& v1) {
    uint4 h;
    h.x = bf_rne(v0.x) | (bf_rne(v0.y) << 16);
    h.y = bf_rne(v0.z) | (bf_rne(v0.w) << 16);
    h.z = bf_rne(v1.x) | (bf_rne(v1.y) << 16);
    h.w = bf_rne(v1.z) | (bf_rne(v1.w) << 16);
    return __builtin_bit_cast(bf16x8, h);
}
// 8 floats -> hi and lo fragments (3-term split precision)
__device__ __forceinline__ void split8hl(const float4& v0, const float4& v1,
                                         bf16x8& hf, bf16x8& lf) {
    float a[8] = {v0.x, v0.y, v0.z, v0.w, v1.x, v1.y, v1.z, v1.w};
    uint4 h, l;
    unsigned hh[8], ll[8];
#pragma unroll
    for (int i = 0; i < 8; i++) {
        hh[i] = bf_rne(a[i]);
        ll[i] = bf_rne(a[i] - bf_to_f(hh[i]));
    }
    h.x = hh[0] | (hh[1] << 16); h.y = hh[2] | (hh[3] << 16);
    h.z = hh[4] | (hh[5] << 16); h.w = hh[6] | (hh[7] << 16);
    l.x = ll[0] | (ll[1] << 16); l.y = ll[2] | (ll[3] << 16);
    l.z = ll[4] | (ll[5] << 16); l.w = ll[6] | (ll[7] << 16);
    hf = __builtin_bit_cast(bf16x8, h);
    lf = __builtin_bit_cast(bf16x8, l);
}

// generic column-split of row-major W[K,N] into frag-layout [kc][c][kk] hi/lo
__device__ __forceinline__ void wsplit(const float* W, int N, int k0, int k1,
                                       unsigned short* H, unsigned short* L, int c) {
    if (c >= N) return;
    for (int k = k0; k < k1; k++) {
        int kc = k >> 5, kk = k & 31;
        float v = W[(size_t)k * N + c];
        unsigned h = bf_rne(v);
        size_t o = ((size_t)kc * N + c) * 32 + kk;
        H[o] = (unsigned short)h;
        L[o] = (unsigned short)bf_rne(v - bf_to_f(h));
    }
}

// ---------------------------------------------------------------------------
// K_prep (grid 519 x 256):
//  blocks 0..510 : Xbf = bf16_hi(X) for nodes [128t,128t+128) ; zero hsum/scores slice
//  block  511    : zero last hsum slice
//  blocks 512..517: weight splits (W0, W2, Wq lo-k, Wq hi-k, Wv, Wo)
//  block  518    : offsets scan
// ---------------------------------------------------------------------------
__global__ __launch_bounds__(256) void k_prep(
    const float* __restrict__ X, const float* __restrict__ W0,
    const float* __restrict__ W2, const float* __restrict__ Wq,
    const float* __restrict__ Wv, const float* __restrict__ Wo,
    const int* __restrict__ lens,
    unsigned short* __restrict__ Xbf,
    unsigned short* __restrict__ W0H, unsigned short* __restrict__ W0L,
    unsigned short* __restrict__ W2H, unsigned short* __restrict__ W2L,
    unsigned short* __restrict__ WqH, unsigned short* __restrict__ WqL,
    unsigned short* __restrict__ WvH, unsigned short* __restrict__ WvL,
    unsigned short* __restrict__ WoH, unsigned short* __restrict__ WoL,
    int* __restrict__ offsets, float* __restrict__ hsum, float* __restrict__ scores)
{
    int blk = blockIdx.x, tid = threadIdx.x;
    if (blk < NTILES) {
        size_t base = (size_t)blk * 16384;
#pragma unroll
        for (int it = 0; it < 8; it++) {
            size_t off = base + it * 2048 + tid * 8;
            const float4* p = (const float4*)(X + off);
            float4 v0 = p[0], v1 = p[1];
            *(uint4*)(Xbf + off) = __builtin_bit_cast(uint4, pack_hi8(v0, v1));
        }
        if (tid < 128) {
            hsum[blk * 128 + tid] = 0.f;
            scores[blk * 128 + tid] = 0.f;
        }
    } else if (blk == 511) {
        if (tid < 128) hsum[511 * 128 + tid] = 0.f;
    } else if (blk == 512) {
        wsplit(W0, FD, 0, 128, W0H, W0L, tid);
    } else if (blk == 513) {
        wsplit(W2, OUT_D, 0, 256, W2H, W2L, tid < 128 ? tid : 9999);
    } else if (blk == 514) {
        wsplit(Wq, FD, 0, 256, WqH, WqL, tid);
    } else if (blk == 515) {
        wsplit(Wq, FD, 256, 512, WqH, WqL, tid);
    } else if (blk == 516) {
        wsplit(Wv, FD, 0, 256, WvH, WvL, tid);
    } else if (blk == 517) {
        wsplit(Wo, HID, 0, 256, WoH, WoL, tid);
    } else {
        __shared__ int sc[B_G];
        sc[tid] = lens[tid];
        __syncthreads();
        for (int d = 1; d < 256; d <<= 1) {
            int v = (tid >= d) ? sc[tid - d] : 0;
            __syncthreads();
            sc[tid] += v;
            __syncthreads();
        }
        offsets[tid + 1] = sc[tid];
        if (tid == 0) offsets[0] = 0;
    }
}

// ---------------------------------------------------------------------------
// K_q (grid 16): q[256,256] = TE @ WqS + bq   (3-term MFMA, weights read once)
// block = 64 rows x 64 cols; wave w = rows [16w,16w+16); K=512
// ---------------------------------------------------------------------------
__global__ __launch_bounds__(256) void k_q(
    const float* __restrict__ TE,
    const unsigned short* __restrict__ WqH, const unsigned short* __restrict__ WqL,
    const float* __restrict__ bq, float* __restrict__ q)
{
    int blk = blockIdx.x;
    int rbase = (blk >> 2) * 64, cbase = (blk & 3) * 64;
    int tid = threadIdx.x, lane = tid & 63, w = tid >> 6;
    int ln = lane & 15, quad = lane >> 4;

    f32x4 acc[4] = {};
    int arow = rbase + w * 16 + ln;
#pragma unroll
    for (int kc = 0; kc < 16; kc++) {
        const float4* ap = (const float4*)(TE + (size_t)arow * TXT + kc * 32 + quad * 8);
        bf16x8 AH, AL;
        split8hl(ap[0], ap[1], AH, AL);
#pragma unroll
        for (int j = 0; j < 4; j++) {
            int c = cbase + 16 * j + ln;
            size_t bo = ((size_t)kc * 256 + c) * 32 + quad * 8;
            bf16x8 BH = *(const bf16x8*)(WqH + bo);
            bf16x8 BL = *(const bf16x8*)(WqL + bo);
            acc[j] = MFMA(AH, BH, acc[j]);
            acc[j] = MFMA(AH, BL, acc[j]);
            acc[j] = MFMA(AL, BH, acc[j]);
        }
    }
#pragma unroll
    for (int j = 0; j < 4; j++) {
        int c = cbase + 16 * j + ln;
        float bb = bq[c];
#pragma unroll
        for (int r = 0; r < 4; r++) {
            int row = rbase + w * 16 + quad * 4 + r;
            q[(size_t)row * FD + c] = acc[j][r] + bb;
        }
    }
}

// ---------------------------------------------------------------------------
// K_qk (grid 16): qk[b,f] = sum_c q[b,c] * Wk[f,c]   (B direct from Wk rows)
// ---------------------------------------------------------------------------
__global__ __launch_bounds__(256) void k_qk(
    const float* __restrict__ q, const float* __restrict__ Wk,
    float* __restrict__ qk)
{
    int blk = blockIdx.x;
    int rbase = (blk >> 2) * 64, cbase = (blk & 3) * 64;
    int tid = threadIdx.x, lane = tid & 63, w = tid >> 6;
    int ln = lane & 15, quad = lane >> 4;

    f32x4 acc[4] = {};
    int arow = rbase + w * 16 + ln;
#pragma unroll
    for (int kc = 0; kc < 8; kc++) {
        const float4* ap = (const float4*)(q + (size_t)arow * FD + kc * 32 + quad * 8);
        bf16x8 AH, AL;
        split8hl(ap[0], ap[1], AH, AL);
#pragma unroll
        for (int j = 0; j < 4; j++) {
            int f = cbase + 16 * j + ln;
            const float4* bp = (const float4*)(Wk + (size_t)f * FD + kc * 32 + quad * 8);
            bf16x8 BH, BL;
            split8hl(bp[0], bp[1], BH, BL);
            acc[j] = MFMA(AH, BH, acc[j]);
            acc[j] = MFMA(AH, BL, acc[j]);
            acc[j] = MFMA(AL, BH, acc[j]);
        }
    }
#pragma unroll
    for (int j = 0; j < 4; j++) {
        int f = cbase + 16 * j + ln;
#pragma unroll
        for (int r = 0; r < 4; r++) {
            int row = rbase + w * 16 + quad * 4 + r;
            qk[(size_t)row * FD + f] = acc[j][r];
        }
    }
}

// ---------------------------------------------------------------------------
// K_l0 (grid 2 x 511): h = relu(Xbf @ W0 + b0) over packed 128-node tiles.
// scores += h . qk[seg(n)] (atomic), hsum[seg(n)] += col-sums (atomic).
// Tile spans <= 2 graphs (min len 128); per-node graph-bit via offsets search.
// ---------------------------------------------------------------------------
__global__ __launch_bounds__(256) void k_l0(
    const unsigned short* __restrict__ Xbf,
    const unsigned short* __restrict__ W0H, const unsigned short* __restrict__ W0L,
    const float* __restrict__ b0, const float* __restrict__ qk,
    const int* __restrict__ offsets,
    float* __restrict__ scores, float* __restrict__ hsum)
{
    int t = blockIdx.y, bx = blockIdx.x;
    int n0 = t * 128;
    int tid = threadIdx.x, lane = tid & 63, w = tid >> 6;
    int ln = lane & 15, quad = lane >> 4;
    int i2 = w & 1, j2 = w >> 1;

    __shared__ __align__(16) unsigned short Xs[128 * XKS];
    __shared__ int offs[257];
    __shared__ float qks[2][128];
    __shared__ float bsh[128];

    offs[tid] = offsets[tid];
    if (tid == 0) offs[256] = offsets[256];
    __syncthreads();

    // binary search: g0 = graph of n0, g1 = graph of n0+127
    int lo = 0, hi = 255;
#pragma unroll
    for (int s = 0; s < 8; s++) {
        int mid = (lo + hi + 1) >> 1;
        if (offs[mid] <= n0) lo = mid; else hi = mid - 1;
    }
    int g0 = lo;
    lo = g0; hi = 255;
#pragma unroll
    for (int s = 0; s < 8; s++) {
        int mid = (lo + hi + 1) >> 1;
        if (offs[mid] <= n0 + 127) lo = mid; else hi = mid - 1;
    }
    int g1 = lo;
    int boundary = (g1 > g0) ? offs[g1] : 0x7fffffff;

    if (tid < 128) {
        bsh[tid] = b0[bx * 128 + tid];
        qks[0][tid] = qk[(size_t)g0 * FD + bx * 128 + tid];
        qks[1][tid] = qk[(size_t)g1 * FD + bx * 128 + tid];
    }
    // stage Xbf tile (128 x 128 bf16) once
#pragma unroll
    for (int it = 0; it < 8; it++) {
        int row = it * 16 + (tid >> 4);
        int kq = (tid & 15) * 8;
        *(uint4*)(Xs + row * XKS + kq) =
            *(const uint4*)(Xbf + (size_t)(n0 + row) * IN_D + kq);
    }
    __syncthreads();

    f32x4 acc[4][4] = {};
#pragma unroll
    for (int kc = 0; kc < 4; kc++) {
        bf16x8 AH[4], BH[4], BL[4];
#pragma unroll
        for (int i = 0; i < 4; i++)
            AH[i] = *(const bf16x8*)(Xs + (i2 * 64 + 16 * i + ln) * XKS + kc * 32 + quad * 8);
#pragma unroll
        for (int j = 0; j < 4; j++) {
            int c = bx * 128 + j2 * 64 + 16 * j + ln;
            size_t bo = ((size_t)kc * 256 + c) * 32 + quad * 8;
            BH[j] = *(const bf16x8*)(W0H + bo);
            BL[j] = *(const bf16x8*)(W0L + bo);
        }
#pragma unroll
        for (int i = 0; i < 4; i++)
#pragma unroll
            for (int j = 0; j < 4; j++) {
                acc[i][j] = MFMA(AH[i], BH[j], acc[i][j]);
                acc[i][j] = MFMA(AH[i], BL[j], acc[i][j]);
            }
    }

    // epilogue: bias+relu -> score partials (per node) & seg col-sums
    float sp[4][4];
    float cs[4][2];
#pragma unroll
    for (int i = 0; i < 4; i++)
#pragma unroll
        for (int r = 0; r < 4; r++) sp[i][r] = 0.f;
#pragma unroll
    for (int j = 0; j < 4; j++) { cs[j][0] = 0.f; cs[j][1] = 0.f; }

#pragma unroll
    for (int i = 0; i < 4; i++)
#pragma unroll
        for (int j = 0; j < 4; j++) {
            int cl = j2 * 64 + 16 * j + ln;
            float bb = bsh[cl];
#pragma unroll
            for (int r = 0; r < 4; r++) {
                int node = i2 * 64 + 16 * i + quad * 4 + r;
                int gb = (n0 + node >= boundary) ? 1 : 0;
                float h = fmaxf(acc[i][j][r] + bb, 0.f);
                sp[i][r] = fmaf(h, qks[gb][cl], sp[i][r]);
                cs[j][gb] += h;
            }
        }
    // scores: reduce over ln
#pragma unroll
    for (int i = 0; i < 4; i++)
#pragma unroll
        for (int r = 0; r < 4; r++) {
            float s = sp[i][r];
            s += __shfl_xor(s, 1); s += __shfl_xor(s, 2);
            s += __shfl_xor(s, 4); s += __shfl_xor(s, 8);
            if (ln == 0) {
                int node = i2 * 64 + 16 * i + quad * 4 + r;
                atomicAdd(&scores[n0 + node], s);
            }
        }
    // hsum: reduce over quads
#pragma unroll
    for (int j = 0; j < 4; j++) {
        int cl = j2 * 64 + 16 * j + ln;
#pragma unroll
        for (int gb = 0; gb < 2; gb++) {
            float s = cs[j][gb];
            s += __shfl_xor(s, 16); s += __shfl_xor(s, 32);
            if (quad == 0 && (gb == 0 || g1 > g0)) {
                int g = gb ? g1 : g0;
                atomicAdd(&hsum[(size_t)g * FD + bx * 128 + cl], s);
            }
        }
    }
}

// ---------------------------------------------------------------------------
// K_mid (grid 260):
//  blocks 0..3  : vsum = hsum@WvS + len*bv (LDS) ; wvec = vsum@WoS  (GEMM chain)
//  blocks 4..259: per-graph softmax stats (smax, dinv)
// ---------------------------------------------------------------------------
__global__ __launch_bounds__(256) void k_mid(
    const float* __restrict__ scores, const float* __restrict__ hsum,
    const unsigned short* __restrict__ WvH, const unsigned short* __restrict__ WvL,
    const float* __restrict__ bv,
    const unsigned short* __restrict__ WoH, const unsigned short* __restrict__ WoL,
    const int* __restrict__ offsets,
    float* __restrict__ wvec, float* __restrict__ smax, float* __restrict__ dinv)
{
    int blk = blockIdx.x, tid = threadIdx.x;
    if (blk < 4) {
        __shared__ float vs[64 * 260];
        __shared__ int offs2[65];
        int base = blk * 64;
        int lane = tid & 63, w = tid >> 6;
        int ln = lane & 15, quad = lane >> 4;
        if (tid < 65) offs2[tid] = offsets[base + tid];
        __syncthreads();

        // phase 1: vsum = hsum @ Wv + len*bv
        f32x4 acc[4][4] = {};
#pragma unroll
        for (int kc = 0; kc < 8; kc++) {
            bf16x8 AH[4], AL[4], BH[4], BL[4];
#pragma unroll
            for (int i = 0; i < 4; i++) {
                const float4* ap = (const float4*)(hsum + (size_t)(base + 16 * i + ln) * FD + kc * 32 + quad * 8);
                split8hl(ap[0], ap[1], AH[i], AL[i]);
            }
#pragma unroll
            for (int j = 0; j < 4; j++) {
                int c = w * 64 + 16 * j + ln;
                size_t bo = ((size_t)kc * 256 + c) * 32 + quad * 8;
                BH[j] = *(const bf16x8*)(WvH + bo);
                BL[j] = *(const bf16x8*)(WvL + bo);
            }
#pragma unroll
            for (int i = 0; i < 4; i++)
#pragma unroll
                for (int j = 0; j < 4; j++) {
                    acc[i][j] = MFMA(AH[i], BH[j], acc[i][j]);
                    acc[i][j] = MFMA(AH[i], BL[j], acc[i][j]);
                    acc[i][j] = MFMA(AL[i], BH[j], acc[i][j]);
                }
        }
#pragma unroll
        for (int i = 0; i < 4; i++)
#pragma unroll
            for (int j = 0; j < 4; j++) {
                int c = w * 64 + 16 * j + ln;
                float bvc = bv[c];
#pragma unroll
                for (int r = 0; r < 4; r++) {
                    int row = 16 * i + quad * 4 + r;
                    float len = (float)(offs2[row + 1] - offs2[row]);
                    vs[row * 260 + c] = acc[i][j][r] + len * bvc;
                }
            }
        __syncthreads();

        // phase 2: wvec = vsum @ Wo
        f32x4 acc2[4][4] = {};
#pragma unroll
        for (int kc = 0; kc < 8; kc++) {
            bf16x8 AH[4], AL[4], BH[4], BL[4];
#pragma unroll
            for (int i = 0; i < 4; i++) {
                const float4* ap = (const float4*)(vs + (16 * i + ln) * 260 + kc * 32 + quad * 8);
                split8hl(ap[0], ap[1], AH[i], AL[i]);
            }
#pragma unroll
            for (int j = 0; j < 4; j++) {
                int c = w * 64 + 16 * j + ln;
                size_t bo = ((size_t)kc * 256 + c) * 32 + quad * 8;
                BH[j] = *(const bf16x8*)(WoH + bo);
                BL[j] = *(const bf16x8*)(WoL + bo);
            }
#pragma unroll
            for (int i = 0; i < 4; i++)
#pragma unroll
                for (int j = 0; j < 4; j++) {
                    acc2[i][j] = MFMA(AH[i], BH[j], acc2[i][j]);
                    acc2[i][j] = MFMA(AH[i], BL[j], acc2[i][j]);
                    acc2[i][j] = MFMA(AL[i], BH[j], acc2[i][j]);
                }
        }
#pragma unroll
        for (int i = 0; i < 4; i++)
#pragma unroll
            for (int j = 0; j < 4; j++) {
                int c = w * 64 + 16 * j + ln;
#pragma unroll
                for (int r = 0; r < 4; r++) {
                    int row = 16 * i + quad * 4 + r;
                    wvec[(size_t)(base + row) * HID + c] = acc2[i][j][r];
                }
            }
    } else {
        int b = blk - 4;
        int off = offsets[b], len = offsets[b + 1] - off;
        __shared__ float redm[4], reds[4];
        float m = -INFINITY;
        for (int i = tid; i < len; i += 256) m = fmaxf(m, scores[off + i]);
        for (int d = 1; d < 64; d <<= 1) m = fmaxf(m, __shfl_xor(m, d));
        if ((tid & 63) == 0) redm[tid >> 6] = m;
        __syncthreads();
        m = fmaxf(fmaxf(redm[0], redm[1]), fmaxf(redm[2], redm[3]));
        float s = 0.f;
        for (int i = tid; i < len; i += 256) s += expf(scores[off + i] - m);
        for (int d = 1; d < 64; d <<= 1) s += __shfl_xor(s, d);
        if ((tid & 63) == 0) reds[tid >> 6] = s;
        __syncthreads();
        if (tid == 0) {
            smax[b] = m;
            dinv[b] = 1.0f / (reds[0] + reds[1] + reds[2] + reds[3]);
        }
    }
}

// ---------------------------------------------------------------------------
// K_fin (grid 511): y = relu(p_n * wvec[seg] + bo) @ W2 + b2 over full tiles.
// A generated in-reg; B direct from W2S (L2-hot). All nodes valid.
// ---------------------------------------------------------------------------
__global__ __launch_bounds__(256) void k_fin(
    const float* __restrict__ scores, const float* __restrict__ wvec,
    const float* __restrict__ bo,
    const unsigned short* __restrict__ W2H, const unsigned short* __restrict__ W2L,
    const float* __restrict__ b2, const float* __restrict__ smax,
    const float* __restrict__ dinv, const int* __restrict__ offsets,
    float* __restrict__ Y)
{
    int t = blockIdx.x;
    int n0 = t * 128;
    int tid = threadIdx.x, lane = tid & 63, w = tid >> 6;
    int ln = lane & 15, quad = lane >> 4;
    int i2 = w & 1, j2 = w >> 1;

    __shared__ int offs[257];
    __shared__ float wsh[2][HID];
    __shared__ float bosh[HID];
    __shared__ float b2sh[OUT_D];
    __shared__ float sd[4];   // smax[g0], dinv[g0], smax[g1], dinv[g1]

    offs[tid] = offsets[tid];
    if (tid == 0) offs[256] = offsets[256];
    __syncthreads();

    int lo = 0, hi = 255;
#pragma unroll
    for (int s = 0; s < 8; s++) {
        int mid = (lo + hi + 1) >> 1;
        if (offs[mid] <= n0) lo = mid; else hi = mid - 1;
    }
    int g0 = lo;
    lo = g0; hi = 255;
#pragma unroll
    for (int s = 0; s < 8; s++) {
        int mid = (lo + hi + 1) >> 1;
        if (offs[mid] <= n0 + 127) lo = mid; else hi = mid - 1;
    }
    int g1 = lo;
    int boundary = (g1 > g0) ? offs[g1] : 0x7fffffff;

    wsh[0][tid] = wvec[(size_t)g0 * HID + tid];
    wsh[1][tid] = wvec[(size_t)g1 * HID + tid];
    bosh[tid] = bo[tid];
    if (tid < OUT_D) b2sh[tid] = b2[tid];
    if (tid == 0) { sd[0] = smax[g0]; sd[1] = dinv[g0]; sd[2] = smax[g1]; sd[3] = dinv[g1]; }
    __syncthreads();

    // per-lane p for its 4 A-rows
    float p[4];
    int gb_i[4];
#pragma unroll
    for (int i = 0; i < 4; i++) {
        int node = i2 * 64 + 16 * i + ln;
        int gb = (n0 + node >= boundary) ? 1 : 0;
        gb_i[i] = gb;
        p[i] = expf(scores[n0 + node] - sd[gb * 2]) * sd[gb * 2 + 1];
    }

    f32x4 acc[4][4] = {};
#pragma unroll
    for (int kc = 0; kc < 8; kc++) {
        float4 bo0 = *(const float4*)&bosh[kc * 32 + quad * 8];
        float4 bo1 = *(const float4*)&bosh[kc * 32 + quad * 8 + 4];
        bf16x8 AH[4], BH[4], BL[4];
#pragma unroll
        for (int i = 0; i < 4; i++) {
            float4 wv0 = *(const float4*)&wsh[gb_i[i]][kc * 32 + quad * 8];
            float4 wv1 = *(const float4*)&wsh[gb_i[i]][kc * 32 + quad * 8 + 4];
            float4 z0, z1;
            z0.x = fmaxf(fmaf(p[i], wv0.x, bo0.x), 0.f);
            z0.y = fmaxf(fmaf(p[i], wv0.y, bo0.y), 0.f);
            z0.z = fmaxf(fmaf(p[i], wv0.z, bo0.z), 0.f);
            z0.w = fmaxf(fmaf(p[i], wv0.w, bo0.w), 0.f);
            z1.x = fmaxf(fmaf(p[i], wv1.x, bo1.x), 0.f);
            z1.y = fmaxf(fmaf(p[i], wv1.y, bo1.y), 0.f);
            z1.z = fmaxf(fmaf(p[i], wv1.z, bo1.z), 0.f);
            z1.w = fmaxf(fmaf(p[i], wv1.w, bo1.w), 0.f);
            AH[i] = pack_hi8(z0, z1);
        }
#pragma unroll
        for (int j = 0; j < 4; j++) {
            int c = j2 * 64 + 16 * j + ln;
            size_t boff = ((size_t)kc * 128 + c) * 32 + quad * 8;
            BH[j] = *(const bf16x8*)(W2H + boff);
            BL[j] = *(const bf16x8*)(W2L + boff);
        }
#pragma unroll
        for (int i = 0; i < 4; i++)
#pragma unroll
            for (int j = 0; j < 4; j++) {
                acc[i][j] = MFMA(AH[i], BH[j], acc[i][j]);
                acc[i][j] = MFMA(AH[i], BL[j], acc[i][j]);
            }
    }

#pragma unroll
    for (int i = 0; i < 4; i++)
#pragma unroll
        for (int j = 0; j < 4; j++) {
            int c = j2 * 64 + 16 * j + ln;
            float bb = b2sh[c];
#pragma unroll
            for (int r = 0; r < 4; r++) {
                int node = i2 * 64 + 16 * i + quad * 4 + r;
                Y[(size_t)(n0 + node) * OUT_D + c] = acc[i][j][r] + bb;
            }
        }
}

// ---------------------------------------------------------------------------
extern "C" void kernel_launch(void* const* d_in, const int* in_sizes, int n_in,
                              void* d_out, int out_size, void* d_ws, size_t ws_size,
                              hipStream_t stream)
{
    const float* X        = (const float*)d_in[0];
    const float* text_emb = (const float*)d_in[1];
    const int*   lens     = (const int*)d_in[2];
    const float* W0       = (const float*)d_in[3];
    const float* b0       = (const float*)d_in[4];
    const float* Wq       = (const float*)d_in[5];
    const float* bq       = (const float*)d_in[6];
    const float* Wk       = (const float*)d_in[7];
    // d_in[8] = bk : softmax-invariant, unused
    const float* Wv       = (const float*)d_in[9];
    const float* bv       = (const float*)d_in[10];
    const float* Wo       = (const float*)d_in[11];
    const float* bo       = (const float*)d_in[12];
    const float* W2       = (const float*)d_in[13];
    const float* b2       = (const float*)d_in[14];
    float* Y = (float*)d_out;

    char* base = (char*)d_ws;
    size_t o = 0;
    int*   offsets = (int*)(base + o);                  o += 4096;
    float* qbuf    = (float*)(base + o);                o += 262144;
    float* qkbuf   = (float*)(base + o);                o += 262144;
    float* wvec    = (float*)(base + o);                o += 262144;
    float* smaxb   = (float*)(base + o);                o += 1024;
    float* dinvb   = (float*)(base + o);                o += 1024;
    float* hsum    = (float*)(base + o);                o += 262144;
    float* scores  = (float*)(base + o);                o += 262144;
    unsigned short* WqH = (unsigned short*)(base + o);  o += 262144;
    unsigned short* WqL = (unsigned short*)(base + o);  o += 262144;
    unsigned short* WvH = (unsigned short*)(base + o);  o += 131072;
    unsigned short* WvL = (unsigned short*)(base + o);  o += 131072;
    unsigned short* WoH = (unsigned short*)(base + o);  o += 131072;
    unsigned short* WoL = (unsigned short*)(base + o);  o += 131072;
    unsigned short* W0H = (unsigned short*)(base + o);  o += 65536;
    unsigned short* W0L = (unsigned short*)(base + o);  o += 65536;
    unsigned short* W2H = (unsigned short*)(base + o);  o += 65536;
    unsigned short* W2L = (unsigned short*)(base + o);  o += 65536;
    unsigned short* Xbf = (unsigned short*)(base + o);  o += 16744448;

    k_prep<<<519, 256, 0, stream>>>(X, W0, W2, Wq, Wv, Wo, lens, Xbf,
                                    W0H, W0L, W2H, W2L, WqH, WqL, WvH, WvL,
                                    WoH, WoL, offsets, hsum, scores);
    k_q<<<16, 256, 0, stream>>>(text_emb, WqH, WqL, bq, qbuf);
    k_qk<<<16, 256, 0, stream>>>(qbuf, Wk, qkbuf);
    k_l0<<<dim3(2, NTILES), 256, 0, stream>>>(Xbf, W0H, W0L, b0, qkbuf, offsets, scores, hsum);
    k_mid<<<260, 256, 0, stream>>>(scores, hsum, WvH, WvL, bv, WoH, WoL, offsets,
                                   wvec, smaxb, dinvb);
    k_fin<<<NTILES, 256, 0, stream>>>(scores, wvec, bo, W2H, W2L, b2, smaxb, dinvb,
                                      offsets, Y);
}

// Round 7
// 228.375 us; speedup vs baseline: 1.3053x; 1.3053x over previous
//
#include <hip/hip_runtime.h>
#include <math.h>

#define B_G   256
#define IN_D  128
#define FD    256
#define HID   256
#define OUT_D 128
#define TXT   512
#define NTILES 511          // N = 65408 = 511 * 128 exactly
#define XKS   136           // LDS k-stride for staged Xbf tile (ushorts)

typedef short bf16x8 __attribute__((ext_vector_type(8)));
typedef float f32x4  __attribute__((ext_vector_type(4)));

__device__ __forceinline__ f32x4 MFMA(bf16x8 a, bf16x8 b, f32x4 c) {
    return __builtin_amdgcn_mfma_f32_16x16x32_bf16(a, b, c, 0, 0, 0);
}

// ---------------------------------------------------------------------------
// bf16 helpers (RNE)
// ---------------------------------------------------------------------------
__device__ __forceinline__ unsigned bf_rne(float x) {
    unsigned u = __float_as_uint(x);
    u += 0x7fffu + ((u >> 16) & 1u);
    return u >> 16;
}
__device__ __forceinline__ float bf_to_f(unsigned h) {
    return __uint_as_float(h << 16);
}
__device__ __forceinline__ bf16x8 pack_hi8(const float4& v0, const float4& v1) {
    uint4 h;
    h.x = bf_rne(v0.x) | (bf_rne(v0.y) << 16);
    h.y = bf_rne(v0.z) | (bf_rne(v0.w) << 16);
    h.z = bf_rne(v1.x) | (bf_rne(v1.y) << 16);
    h.w = bf_rne(v1.z) | (bf_rne(v1.w) << 16);
    return __builtin_bit_cast(bf16x8, h);
}
// 8 floats -> hi and lo fragments (3-term split precision)
__device__ __forceinline__ void split8hl(const float4& v0, const float4& v1,
                                         bf16x8& hf, bf16x8& lf) {
    float a[8] = {v0.x, v0.y, v0.z, v0.w, v1.x, v1.y, v1.z, v1.w};
    uint4 h, l;
    unsigned hh[8], ll[8];
#pragma unroll
    for (int i = 0; i < 8; i++) {
        hh[i] = bf_rne(a[i]);
        ll[i] = bf_rne(a[i] - bf_to_f(hh[i]));
    }
    h.x = hh[0] | (hh[1] << 16); h.y = hh[2] | (hh[3] << 16);
    h.z = hh[4] | (hh[5] << 16); h.w = hh[6] | (hh[7] << 16);
    l.x = ll[0] | (ll[1] << 16); l.y = ll[2] | (ll[3] << 16);
    l.z = ll[4] | (ll[5] << 16); l.w = ll[6] | (ll[7] << 16);
    hf = __builtin_bit_cast(bf16x8, h);
    lf = __builtin_bit_cast(bf16x8, l);
}

// ---------------------------------------------------------------------------
// K_wsplit (grid 44 x 256): parallel weight split, one block per (matrix, kc).
// Thread t = column c: 32 coalesced row-loads, pack in regs, one 64 B
// contiguous store each to H and L (fragment layout [kc][c][kk]).
//  blocks 0..3  : W0 (K=128, N=256)
//  blocks 4..11 : W2 (K=256, N=128)
//  blocks 12..27: Wq (K=512, N=256)
//  blocks 28..35: Wv (K=256, N=256)
//  blocks 36..43: Wo (K=256, N=256)
// ---------------------------------------------------------------------------
__global__ __launch_bounds__(256) void k_wsplit(
    const float* __restrict__ W0, const float* __restrict__ W2,
    const float* __restrict__ Wq, const float* __restrict__ Wv,
    const float* __restrict__ Wo,
    unsigned short* __restrict__ W0H, unsigned short* __restrict__ W0L,
    unsigned short* __restrict__ W2H, unsigned short* __restrict__ W2L,
    unsigned short* __restrict__ WqH, unsigned short* __restrict__ WqL,
    unsigned short* __restrict__ WvH, unsigned short* __restrict__ WvL,
    unsigned short* __restrict__ WoH, unsigned short* __restrict__ WoL)
{
    int blk = blockIdx.x, c = threadIdx.x;
    const float* W; unsigned short* H; unsigned short* L; int N, kc;
    if (blk < 4)       { W = W0; H = W0H; L = W0L; N = 256; kc = blk; }
    else if (blk < 12) { W = W2; H = W2H; L = W2L; N = 128; kc = blk - 4; }
    else if (blk < 28) { W = Wq; H = WqH; L = WqL; N = 256; kc = blk - 12; }
    else if (blk < 36) { W = Wv; H = WvH; L = WvL; N = 256; kc = blk - 28; }
    else               { W = Wo; H = WoH; L = WoL; N = 256; kc = blk - 36; }
    if (c >= N) return;

    unsigned hw[16], lw[16];
#pragma unroll
    for (int kk = 0; kk < 32; kk++) {
        float v = W[(size_t)(kc * 32 + kk) * N + c];
        unsigned h = bf_rne(v);
        unsigned l = bf_rne(v - bf_to_f(h));
        if (kk & 1) { hw[kk >> 1] |= h << 16; lw[kk >> 1] |= l << 16; }
        else        { hw[kk >> 1] = h;        lw[kk >> 1] = l; }
    }
    size_t o = ((size_t)kc * N + c) * 32;
    uint4* hp = (uint4*)(H + o);
    uint4* lp = (uint4*)(L + o);
#pragma unroll
    for (int r = 0; r < 4; r++) {
        hp[r] = make_uint4(hw[r * 4], hw[r * 4 + 1], hw[r * 4 + 2], hw[r * 4 + 3]);
        lp[r] = make_uint4(lw[r * 4], lw[r * 4 + 1], lw[r * 4 + 2], lw[r * 4 + 3]);
    }
}

// ---------------------------------------------------------------------------
// K_prep (grid 512 x 256):
//  blocks 0..510 : Xbf = bf16_hi(X) for nodes [128t,128t+128) ; zero hsum/scores
//  block  511    : zero last hsum slice + offsets scan
// ---------------------------------------------------------------------------
__global__ __launch_bounds__(256) void k_prep(
    const float* __restrict__ X, const int* __restrict__ lens,
    unsigned short* __restrict__ Xbf, int* __restrict__ offsets,
    float* __restrict__ hsum, float* __restrict__ scores)
{
    int blk = blockIdx.x, tid = threadIdx.x;
    if (blk < NTILES) {
        size_t base = (size_t)blk * 16384;
#pragma unroll
        for (int it = 0; it < 8; it++) {
            size_t off = base + it * 2048 + tid * 8;
            const float4* p = (const float4*)(X + off);
            float4 v0 = p[0], v1 = p[1];
            *(uint4*)(Xbf + off) = __builtin_bit_cast(uint4, pack_hi8(v0, v1));
        }
        if (tid < 128) {
            hsum[blk * 128 + tid] = 0.f;
            scores[blk * 128 + tid] = 0.f;
        }
    } else {
        if (tid < 128) hsum[511 * 128 + tid] = 0.f;
        __shared__ int sc[B_G];
        sc[tid] = lens[tid];
        __syncthreads();
        for (int d = 1; d < 256; d <<= 1) {
            int v = (tid >= d) ? sc[tid - d] : 0;
            __syncthreads();
            sc[tid] += v;
            __syncthreads();
        }
        offsets[tid + 1] = sc[tid];
        if (tid == 0) offsets[0] = 0;
    }
}

// ---------------------------------------------------------------------------
// K_q (grid 16): q[256,256] = TE @ WqS + bq   (3-term MFMA, weights read once)
// ---------------------------------------------------------------------------
__global__ __launch_bounds__(256) void k_q(
    const float* __restrict__ TE,
    const unsigned short* __restrict__ WqH, const unsigned short* __restrict__ WqL,
    const float* __restrict__ bq, float* __restrict__ q)
{
    int blk = blockIdx.x;
    int rbase = (blk >> 2) * 64, cbase = (blk & 3) * 64;
    int tid = threadIdx.x, lane = tid & 63, w = tid >> 6;
    int ln = lane & 15, quad = lane >> 4;

    f32x4 acc[4] = {};
    int arow = rbase + w * 16 + ln;
#pragma unroll
    for (int kc = 0; kc < 16; kc++) {
        const float4* ap = (const float4*)(TE + (size_t)arow * TXT + kc * 32 + quad * 8);
        bf16x8 AH, AL;
        split8hl(ap[0], ap[1], AH, AL);
#pragma unroll
        for (int j = 0; j < 4; j++) {
            int c = cbase + 16 * j + ln;
            size_t bo = ((size_t)kc * 256 + c) * 32 + quad * 8;
            bf16x8 BH = *(const bf16x8*)(WqH + bo);
            bf16x8 BL = *(const bf16x8*)(WqL + bo);
            acc[j] = MFMA(AH, BH, acc[j]);
            acc[j] = MFMA(AH, BL, acc[j]);
            acc[j] = MFMA(AL, BH, acc[j]);
        }
    }
#pragma unroll
    for (int j = 0; j < 4; j++) {
        int c = cbase + 16 * j + ln;
        float bb = bq[c];
#pragma unroll
        for (int r = 0; r < 4; r++) {
            int row = rbase + w * 16 + quad * 4 + r;
            q[(size_t)row * FD + c] = acc[j][r] + bb;
        }
    }
}

// ---------------------------------------------------------------------------
// K_qk (grid 16): qk[b,f] = sum_c q[b,c] * Wk[f,c]
// ---------------------------------------------------------------------------
__global__ __launch_bounds__(256) void k_qk(
    const float* __restrict__ q, const float* __restrict__ Wk,
    float* __restrict__ qk)
{
    int blk = blockIdx.x;
    int rbase = (blk >> 2) * 64, cbase = (blk & 3) * 64;
    int tid = threadIdx.x, lane = tid & 63, w = tid >> 6;
    int ln = lane & 15, quad = lane >> 4;

    f32x4 acc[4] = {};
    int arow = rbase + w * 16 + ln;
#pragma unroll
    for (int kc = 0; kc < 8; kc++) {
        const float4* ap = (const float4*)(q + (size_t)arow * FD + kc * 32 + quad * 8);
        bf16x8 AH, AL;
        split8hl(ap[0], ap[1], AH, AL);
#pragma unroll
        for (int j = 0; j < 4; j++) {
            int f = cbase + 16 * j + ln;
            const float4* bp = (const float4*)(Wk + (size_t)f * FD + kc * 32 + quad * 8);
            bf16x8 BH, BL;
            split8hl(bp[0], bp[1], BH, BL);
            acc[j] = MFMA(AH, BH, acc[j]);
            acc[j] = MFMA(AH, BL, acc[j]);
            acc[j] = MFMA(AL, BH, acc[j]);
        }
    }
#pragma unroll
    for (int j = 0; j < 4; j++) {
        int f = cbase + 16 * j + ln;
#pragma unroll
        for (int r = 0; r < 4; r++) {
            int row = rbase + w * 16 + quad * 4 + r;
            qk[(size_t)row * FD + f] = acc[j][r];
        }
    }
}

// ---------------------------------------------------------------------------
// K_l0 (grid 2 x 511): h = relu(Xbf @ W0 + b0) over packed 128-node tiles.
// ---------------------------------------------------------------------------
__global__ __launch_bounds__(256) void k_l0(
    const unsigned short* __restrict__ Xbf,
    const unsigned short* __restrict__ W0H, const unsigned short* __restrict__ W0L,
    const float* __restrict__ b0, const float* __restrict__ qk,
    const int* __restrict__ offsets,
    float* __restrict__ scores, float* __restrict__ hsum)
{
    int t = blockIdx.y, bx = blockIdx.x;
    int n0 = t * 128;
    int tid = threadIdx.x, lane = tid & 63, w = tid >> 6;
    int ln = lane & 15, quad = lane >> 4;
    int i2 = w & 1, j2 = w >> 1;

    __shared__ __align__(16) unsigned short Xs[128 * XKS];
    __shared__ int offs[257];
    __shared__ float qks[2][128];
    __shared__ float bsh[128];

    offs[tid] = offsets[tid];
    if (tid == 0) offs[256] = offsets[256];
    __syncthreads();

    int lo = 0, hi = 255;
#pragma unroll
    for (int s = 0; s < 8; s++) {
        int mid = (lo + hi + 1) >> 1;
        if (offs[mid] <= n0) lo = mid; else hi = mid - 1;
    }
    int g0 = lo;
    lo = g0; hi = 255;
#pragma unroll
    for (int s = 0; s < 8; s++) {
        int mid = (lo + hi + 1) >> 1;
        if (offs[mid] <= n0 + 127) lo = mid; else hi = mid - 1;
    }
    int g1 = lo;
    int boundary = (g1 > g0) ? offs[g1] : 0x7fffffff;

    if (tid < 128) {
        bsh[tid] = b0[bx * 128 + tid];
        qks[0][tid] = qk[(size_t)g0 * FD + bx * 128 + tid];
        qks[1][tid] = qk[(size_t)g1 * FD + bx * 128 + tid];
    }
#pragma unroll
    for (int it = 0; it < 8; it++) {
        int row = it * 16 + (tid >> 4);
        int kq = (tid & 15) * 8;
        *(uint4*)(Xs + row * XKS + kq) =
            *(const uint4*)(Xbf + (size_t)(n0 + row) * IN_D + kq);
    }
    __syncthreads();

    f32x4 acc[4][4] = {};
#pragma unroll
    for (int kc = 0; kc < 4; kc++) {
        bf16x8 AH[4], BH[4], BL[4];
#pragma unroll
        for (int i = 0; i < 4; i++)
            AH[i] = *(const bf16x8*)(Xs + (i2 * 64 + 16 * i + ln) * XKS + kc * 32 + quad * 8);
#pragma unroll
        for (int j = 0; j < 4; j++) {
            int c = bx * 128 + j2 * 64 + 16 * j + ln;
            size_t bo = ((size_t)kc * 256 + c) * 32 + quad * 8;
            BH[j] = *(const bf16x8*)(W0H + bo);
            BL[j] = *(const bf16x8*)(W0L + bo);
        }
#pragma unroll
        for (int i = 0; i < 4; i++)
#pragma unroll
            for (int j = 0; j < 4; j++) {
                acc[i][j] = MFMA(AH[i], BH[j], acc[i][j]);
                acc[i][j] = MFMA(AH[i], BL[j], acc[i][j]);
            }
    }

    float sp[4][4];
    float cs[4][2];
#pragma unroll
    for (int i = 0; i < 4; i++)
#pragma unroll
        for (int r = 0; r < 4; r++) sp[i][r] = 0.f;
#pragma unroll
    for (int j = 0; j < 4; j++) { cs[j][0] = 0.f; cs[j][1] = 0.f; }

#pragma unroll
    for (int i = 0; i < 4; i++)
#pragma unroll
        for (int j = 0; j < 4; j++) {
            int cl = j2 * 64 + 16 * j + ln;
            float bb = bsh[cl];
#pragma unroll
            for (int r = 0; r < 4; r++) {
                int node = i2 * 64 + 16 * i + quad * 4 + r;
                int gb = (n0 + node >= boundary) ? 1 : 0;
                float h = fmaxf(acc[i][j][r] + bb, 0.f);
                sp[i][r] = fmaf(h, qks[gb][cl], sp[i][r]);
                cs[j][gb] += h;
            }
        }
#pragma unroll
    for (int i = 0; i < 4; i++)
#pragma unroll
        for (int r = 0; r < 4; r++) {
            float s = sp[i][r];
            s += __shfl_xor(s, 1); s += __shfl_xor(s, 2);
            s += __shfl_xor(s, 4); s += __shfl_xor(s, 8);
            if (ln == 0) {
                int node = i2 * 64 + 16 * i + quad * 4 + r;
                atomicAdd(&scores[n0 + node], s);
            }
        }
#pragma unroll
    for (int j = 0; j < 4; j++) {
        int cl = j2 * 64 + 16 * j + ln;
#pragma unroll
        for (int gb = 0; gb < 2; gb++) {
            float s = cs[j][gb];
            s += __shfl_xor(s, 16); s += __shfl_xor(s, 32);
            if (quad == 0 && (gb == 0 || g1 > g0)) {
                int g = gb ? g1 : g0;
                atomicAdd(&hsum[(size_t)g * FD + bx * 128 + cl], s);
            }
        }
    }
}

// ---------------------------------------------------------------------------
// K_mid (grid 260):
//  blocks 0..3  : vsum = hsum@WvS + len*bv ; wvec = vsum@WoS
//  blocks 4..259: per-graph softmax stats
// ---------------------------------------------------------------------------
__global__ __launch_bounds__(256) void k_mid(
    const float* __restrict__ scores, const float* __restrict__ hsum,
    const unsigned short* __restrict__ WvH, const unsigned short* __restrict__ WvL,
    const float* __restrict__ bv,
    const unsigned short* __restrict__ WoH, const unsigned short* __restrict__ WoL,
    const int* __restrict__ offsets,
    float* __restrict__ wvec, float* __restrict__ smax, float* __restrict__ dinv)
{
    int blk = blockIdx.x, tid = threadIdx.x;
    if (blk < 4) {
        __shared__ float vs[64 * 260];
        __shared__ int offs2[65];
        int base = blk * 64;
        int lane = tid & 63, w = tid >> 6;
        int ln = lane & 15, quad = lane >> 4;
        if (tid < 65) offs2[tid] = offsets[base + tid];
        __syncthreads();

        f32x4 acc[4][4] = {};
#pragma unroll
        for (int kc = 0; kc < 8; kc++) {
            bf16x8 AH[4], AL[4], BH[4], BL[4];
#pragma unroll
            for (int i = 0; i < 4; i++) {
                const float4* ap = (const float4*)(hsum + (size_t)(base + 16 * i + ln) * FD + kc * 32 + quad * 8);
                split8hl(ap[0], ap[1], AH[i], AL[i]);
            }
#pragma unroll
            for (int j = 0; j < 4; j++) {
                int c = w * 64 + 16 * j + ln;
                size_t bo = ((size_t)kc * 256 + c) * 32 + quad * 8;
                BH[j] = *(const bf16x8*)(WvH + bo);
                BL[j] = *(const bf16x8*)(WvL + bo);
            }
#pragma unroll
            for (int i = 0; i < 4; i++)
#pragma unroll
                for (int j = 0; j < 4; j++) {
                    acc[i][j] = MFMA(AH[i], BH[j], acc[i][j]);
                    acc[i][j] = MFMA(AH[i], BL[j], acc[i][j]);
                    acc[i][j] = MFMA(AL[i], BH[j], acc[i][j]);
                }
        }
#pragma unroll
        for (int i = 0; i < 4; i++)
#pragma unroll
            for (int j = 0; j < 4; j++) {
                int c = w * 64 + 16 * j + ln;
                float bvc = bv[c];
#pragma unroll
                for (int r = 0; r < 4; r++) {
                    int row = 16 * i + quad * 4 + r;
                    float len = (float)(offs2[row + 1] - offs2[row]);
                    vs[row * 260 + c] = acc[i][j][r] + len * bvc;
                }
            }
        __syncthreads();

        f32x4 acc2[4][4] = {};
#pragma unroll
        for (int kc = 0; kc < 8; kc++) {
            bf16x8 AH[4], AL[4], BH[4], BL[4];
#pragma unroll
            for (int i = 0; i < 4; i++) {
                const float4* ap = (const float4*)(vs + (16 * i + ln) * 260 + kc * 32 + quad * 8);
                split8hl(ap[0], ap[1], AH[i], AL[i]);
            }
#pragma unroll
            for (int j = 0; j < 4; j++) {
                int c = w * 64 + 16 * j + ln;
                size_t bo = ((size_t)kc * 256 + c) * 32 + quad * 8;
                BH[j] = *(const bf16x8*)(WoH + bo);
                BL[j] = *(const bf16x8*)(WoL + bo);
            }
#pragma unroll
            for (int i = 0; i < 4; i++)
#pragma unroll
                for (int j = 0; j < 4; j++) {
                    acc2[i][j] = MFMA(AH[i], BH[j], acc2[i][j]);
                    acc2[i][j] = MFMA(AH[i], BL[j], acc2[i][j]);
                    acc2[i][j] = MFMA(AL[i], BH[j], acc2[i][j]);
                }
        }
#pragma unroll
        for (int i = 0; i < 4; i++)
#pragma unroll
            for (int j = 0; j < 4; j++) {
                int c = w * 64 + 16 * j + ln;
#pragma unroll
                for (int r = 0; r < 4; r++) {
                    int row = 16 * i + quad * 4 + r;
                    wvec[(size_t)(base + row) * HID + c] = acc2[i][j][r];
                }
            }
    } else {
        int b = blk - 4;
        int off = offsets[b], len = offsets[b + 1] - off;
        __shared__ float redm[4], reds[4];
        float m = -INFINITY;
        for (int i = tid; i < len; i += 256) m = fmaxf(m, scores[off + i]);
        for (int d = 1; d < 64; d <<= 1) m = fmaxf(m, __shfl_xor(m, d));
        if ((tid & 63) == 0) redm[tid >> 6] = m;
        __syncthreads();
        m = fmaxf(fmaxf(redm[0], redm[1]), fmaxf(redm[2], redm[3]));
        float s = 0.f;
        for (int i = tid; i < len; i += 256) s += expf(scores[off + i] - m);
        for (int d = 1; d < 64; d <<= 1) s += __shfl_xor(s, d);
        if ((tid & 63) == 0) reds[tid >> 6] = s;
        __syncthreads();
        if (tid == 0) {
            smax[b] = m;
            dinv[b] = 1.0f / (reds[0] + reds[1] + reds[2] + reds[3]);
        }
    }
}

// ---------------------------------------------------------------------------
// K_fin (grid 511): y = relu(p_n * wvec[seg] + bo) @ W2 + b2 over full tiles.
// ---------------------------------------------------------------------------
__global__ __launch_bounds__(256) void k_fin(
    const float* __restrict__ scores, const float* __restrict__ wvec,
    const float* __restrict__ bo,
    const unsigned short* __restrict__ W2H, const unsigned short* __restrict__ W2L,
    const float* __restrict__ b2, const float* __restrict__ smax,
    const float* __restrict__ dinv, const int* __restrict__ offsets,
    float* __restrict__ Y)
{
    int t = blockIdx.x;
    int n0 = t * 128;
    int tid = threadIdx.x, lane = tid & 63, w = tid >> 6;
    int ln = lane & 15, quad = lane >> 4;
    int i2 = w & 1, j2 = w >> 1;

    __shared__ int offs[257];
    __shared__ float wsh[2][HID];
    __shared__ float bosh[HID];
    __shared__ float b2sh[OUT_D];
    __shared__ float sd[4];

    offs[tid] = offsets[tid];
    if (tid == 0) offs[256] = offsets[256];
    __syncthreads();

    int lo = 0, hi = 255;
#pragma unroll
    for (int s = 0; s < 8; s++) {
        int mid = (lo + hi + 1) >> 1;
        if (offs[mid] <= n0) lo = mid; else hi = mid - 1;
    }
    int g0 = lo;
    lo = g0; hi = 255;
#pragma unroll
    for (int s = 0; s < 8; s++) {
        int mid = (lo + hi + 1) >> 1;
        if (offs[mid] <= n0 + 127) lo = mid; else hi = mid - 1;
    }
    int g1 = lo;
    int boundary = (g1 > g0) ? offs[g1] : 0x7fffffff;

    wsh[0][tid] = wvec[(size_t)g0 * HID + tid];
    wsh[1][tid] = wvec[(size_t)g1 * HID + tid];
    bosh[tid] = bo[tid];
    if (tid < OUT_D) b2sh[tid] = b2[tid];
    if (tid == 0) { sd[0] = smax[g0]; sd[1] = dinv[g0]; sd[2] = smax[g1]; sd[3] = dinv[g1]; }
    __syncthreads();

    float p[4];
    int gb_i[4];
#pragma unroll
    for (int i = 0; i < 4; i++) {
        int node = i2 * 64 + 16 * i + ln;
        int gb = (n0 + node >= boundary) ? 1 : 0;
        gb_i[i] = gb;
        p[i] = expf(scores[n0 + node] - sd[gb * 2]) * sd[gb * 2 + 1];
    }

    f32x4 acc[4][4] = {};
#pragma unroll
    for (int kc = 0; kc < 8; kc++) {
        float4 bo0 = *(const float4*)&bosh[kc * 32 + quad * 8];
        float4 bo1 = *(const float4*)&bosh[kc * 32 + quad * 8 + 4];
        bf16x8 AH[4], BH[4], BL[4];
#pragma unroll
        for (int i = 0; i < 4; i++) {
            float4 wv0 = *(const float4*)&wsh[gb_i[i]][kc * 32 + quad * 8];
            float4 wv1 = *(const float4*)&wsh[gb_i[i]][kc * 32 + quad * 8 + 4];
            float4 z0, z1;
            z0.x = fmaxf(fmaf(p[i], wv0.x, bo0.x), 0.f);
            z0.y = fmaxf(fmaf(p[i], wv0.y, bo0.y), 0.f);
            z0.z = fmaxf(fmaf(p[i], wv0.z, bo0.z), 0.f);
            z0.w = fmaxf(fmaf(p[i], wv0.w, bo0.w), 0.f);
            z1.x = fmaxf(fmaf(p[i], wv1.x, bo1.x), 0.f);
            z1.y = fmaxf(fmaf(p[i], wv1.y, bo1.y), 0.f);
            z1.z = fmaxf(fmaf(p[i], wv1.z, bo1.z), 0.f);
            z1.w = fmaxf(fmaf(p[i], wv1.w, bo1.w), 0.f);
            AH[i] = pack_hi8(z0, z1);
        }
#pragma unroll
        for (int j = 0; j < 4; j++) {
            int c = j2 * 64 + 16 * j + ln;
            size_t boff = ((size_t)kc * 128 + c) * 32 + quad * 8;
            BH[j] = *(const bf16x8*)(W2H + boff);
            BL[j] = *(const bf16x8*)(W2L + boff);
        }
#pragma unroll
        for (int i = 0; i < 4; i++)
#pragma unroll
            for (int j = 0; j < 4; j++) {
                acc[i][j] = MFMA(AH[i], BH[j], acc[i][j]);
                acc[i][j] = MFMA(AH[i], BL[j], acc[i][j]);
            }
    }

#pragma unroll
    for (int i = 0; i < 4; i++)
#pragma unroll
        for (int j = 0; j < 4; j++) {
            int c = j2 * 64 + 16 * j + ln;
            float bb = b2sh[c];
#pragma unroll
            for (int r = 0; r < 4; r++) {
                int node = i2 * 64 + 16 * i + quad * 4 + r;
                Y[(size_t)(n0 + node) * OUT_D + c] = acc[i][j][r] + bb;
            }
        }
}

// ---------------------------------------------------------------------------
extern "C" void kernel_launch(void* const* d_in, const int* in_sizes, int n_in,
                              void* d_out, int out_size, void* d_ws, size_t ws_size,
                              hipStream_t stream)
{
    const float* X        = (const float*)d_in[0];
    const float* text_emb = (const float*)d_in[1];
    const int*   lens     = (const int*)d_in[2];
    const float* W0       = (const float*)d_in[3];
    const float* b0       = (const float*)d_in[4];
    const float* Wq       = (const float*)d_in[5];
    const float* bq       = (const float*)d_in[6];
    const float* Wk       = (const float*)d_in[7];
    // d_in[8] = bk : softmax-invariant, unused
    const float* Wv       = (const float*)d_in[9];
    const float* bv       = (const float*)d_in[10];
    const float* Wo       = (const float*)d_in[11];
    const float* bo       = (const float*)d_in[12];
    const float* W2       = (const float*)d_in[13];
    const float* b2       = (const float*)d_in[14];
    float* Y = (float*)d_out;

    char* base = (char*)d_ws;
    size_t o = 0;
    int*   offsets = (int*)(base + o);                  o += 4096;
    float* qbuf    = (float*)(base + o);                o += 262144;
    float* qkbuf   = (float*)(base + o);                o += 262144;
    float* wvec    = (float*)(base + o);                o += 262144;
    float* smaxb   = (float*)(base + o);                o += 1024;
    float* dinvb   = (float*)(base + o);                o += 1024;
    float* hsum    = (float*)(base + o);                o += 262144;
    float* scores  = (float*)(base + o);                o += 262144;
    unsigned short* WqH = (unsigned short*)(base + o);  o += 262144;
    unsigned short* WqL = (unsigned short*)(base + o);  o += 262144;
    unsigned short* WvH = (unsigned short*)(base + o);  o += 131072;
    unsigned short* WvL = (unsigned short*)(base + o);  o += 131072;
    unsigned short* WoH = (unsigned short*)(base + o);  o += 131072;
    unsigned short* WoL = (unsigned short*)(base + o);  o += 131072;
    unsigned short* W0H = (unsigned short*)(base + o);  o += 65536;
    unsigned short* W0L = (unsigned short*)(base + o);  o += 65536;
    unsigned short* W2H = (unsigned short*)(base + o);  o += 65536;
    unsigned short* W2L = (unsigned short*)(base + o);  o += 65536;
    unsigned short* Xbf = (unsigned short*)(base + o);  o += 16744448;

    k_wsplit<<<44, 256, 0, stream>>>(W0, W2, Wq, Wv, Wo,
                                     W0H, W0L, W2H, W2L, WqH, WqL,
                                     WvH, WvL, WoH, WoL);
    k_prep<<<512, 256, 0, stream>>>(X, lens, Xbf, offsets, hsum, scores);
    k_q<<<16, 256, 0, stream>>>(text_emb, WqH, WqL, bq, qbuf);
    k_qk<<<16, 256, 0, stream>>>(qbuf, Wk, qkbuf);
    k_l0<<<dim3(2, NTILES), 256, 0, stream>>>(Xbf, W0H, W0L, b0, qkbuf, offsets, scores, hsum);
    k_mid<<<260, 256, 0, stream>>>(scores, hsum, WvH, WvL, bv, WoH, WoL, offsets,
                                   wvec, smaxb, dinvb);
    k_fin<<<NTILES, 256, 0, stream>>>(scores, wvec, bo, W2H, W2L, b2, smaxb, dinvb,
                                      offsets, Y);
}